// Round 1
// baseline (2467.972 us; speedup 1.0000x reference)
//
#include <hip/hip_runtime.h>
#include <stdint.h>

#define VOCABN 32000
#define EMBEDN 256
#define HIDN   512
#define BN     64
#define SOSID  1
#define EOSID  2

// ---------- helpers ----------
__device__ __forceinline__ unsigned ordf(float f) {
  unsigned u = __float_as_uint(f);
  return (u & 0x80000000u) ? ~u : (u | 0x80000000u);
}
__device__ __forceinline__ int decode_pred(unsigned long long pk) {
  return (int)(0xFFFFFFFFu - (unsigned)(pk & 0xFFFFFFFFull));
}

// ---------- init: h0 = mean(features, axis=1); zero done; zero argmax slots ----------
__global__ void k_init(const float* __restrict__ feat, float* __restrict__ h0,
                       int L, int* __restrict__ done,
                       unsigned long long* __restrict__ slots) {
  int b = blockIdx.x, tid = threadIdx.x;
  float inv = 1.0f / (float)L;
  for (int j = tid; j < HIDN; j += 256) {
    const float* p = feat + (size_t)b * L * HIDN + j;
    float s = 0.f;
    for (int l = 0; l < L; ++l) s += p[(size_t)l * HIDN];
    h0[b * HIDN + j] = s * inv;
  }
  if (b == 0 && tid < 2 * BN) done[tid] = 0;
  if (b == 1 && tid < BN) slots[tid] = 0ull;
}

// ---------- gates: gi = x @ W_ih^T + b_ih ; gh = h @ W_hh^T + b_hh ----------
// grid 192 = 96 n-tiles (32 of 3072) x 2 b-tiles (32 of 64). 256 threads.
// x is gathered from emb[pred] (pred decoded from slots; SOS at t==0).
// block 0 also writes tok[t-1] and updates done (ping-pong).
__global__ __launch_bounds__(256) void k_gates(
    const float* __restrict__ emb, const float* __restrict__ W_ih,
    const float* __restrict__ W_hh, const float* __restrict__ b_ih,
    const float* __restrict__ b_hh, const float* __restrict__ h_rd,
    float* __restrict__ gi, float* __restrict__ gh,
    const unsigned long long* __restrict__ slots,
    const int* __restrict__ done_rd, int* __restrict__ done_wr,
    float* __restrict__ out_toks, int t, int T) {
  __shared__ float Xs[32][68];
  __shared__ float Ws[32][68];
  __shared__ int preds[32];

  int nt = blockIdx.x >> 1;          // 0..95
  int bg = blockIdx.x & 1;           // 0..1
  int n0 = nt * 32;                  // 0..3071 (first 1536 = gi, rest = gh)
  int b0 = bg * 32;
  int tid = threadIdx.x;
  bool is_gi = (n0 < 1536);

  if (tid < 32) {
    int b = b0 + tid;
    preds[tid] = (t == 0) ? SOSID : decode_pred(slots[b]);
  }
  if (blockIdx.x == 0 && t >= 1 && tid < BN) {
    int b = tid;
    int pred = decode_pred(slots[b]);
    int iseos = (pred == EOSID) ? 1 : 0;
    int dold = done_rd[b];
    int tok = (dold || iseos) ? 0 : pred;
    out_toks[(size_t)b * T + (t - 1)] = (float)tok;
    done_wr[b] = dold | iseos;
  }
  __syncthreads();

  int K = is_gi ? EMBEDN : HIDN;
  int tn = tid & 31;                 // n within tile
  int tb = tid >> 5;                 // 8 slots x 4 b
  int nrow = n0 + tn;
  float bias = is_gi ? b_ih[nrow] : b_hh[nrow - 1536];
  float acc[4] = {bias, bias, bias, bias};
  const float* Wsrc = is_gi ? (W_ih + (size_t)n0 * EMBEDN)
                            : (W_hh + (size_t)(n0 - 1536) * HIDN);

  for (int k0 = 0; k0 < K; k0 += 64) {
    #pragma unroll
    for (int p = 0; p < 2; ++p) {
      int idx = tid + p * 256;       // 0..511
      int r = idx >> 4, c4 = idx & 15;
      *(float4*)&Ws[r][c4 * 4] =
          *(const float4*)(Wsrc + (size_t)r * K + k0 + c4 * 4);
      const float* src = is_gi
          ? (emb + (size_t)preds[r] * EMBEDN + k0 + c4 * 4)
          : (h_rd + (size_t)(b0 + r) * HIDN + k0 + c4 * 4);
      *(float4*)&Xs[r][c4 * 4] = *(const float4*)src;
    }
    __syncthreads();
    #pragma unroll
    for (int k4 = 0; k4 < 16; ++k4) {
      float4 w = *(float4*)&Ws[tn][k4 * 4];
      #pragma unroll
      for (int j = 0; j < 4; ++j) {
        float4 x = *(float4*)&Xs[tb * 4 + j][k4 * 4];
        acc[j] += w.x * x.x + w.y * x.y + w.z * x.z + w.w * x.w;
      }
    }
    __syncthreads();
  }

  float* dst = is_gi ? gi : gh;
  int nc = is_gi ? nrow : (nrow - 1536);
  #pragma unroll
  for (int j = 0; j < 4; ++j)
    dst[(size_t)(b0 + tb * 4 + j) * 1536 + nc] = acc[j];
}

// ---------- h update (torch GRUCell combine) + reset argmax slots ----------
__global__ void k_hup(const float* __restrict__ gi, const float* __restrict__ gh,
                      const float* __restrict__ h_old, float* __restrict__ h_new,
                      unsigned long long* __restrict__ slots) {
  int b = blockIdx.x, j = threadIdx.x;  // 64 blocks x 512 threads
  const float* gib = gi + (size_t)b * 1536;
  const float* ghb = gh + (size_t)b * 1536;
  float r = 1.f / (1.f + __expf(0.f) * 0.f + expf(-(gib[j] + ghb[j])));
  float z = 1.f / (1.f + expf(-(gib[512 + j] + ghb[512 + j])));
  float n = tanhf(gib[1024 + j] + r * ghb[1024 + j]);
  float ho = h_old[b * HIDN + j];
  h_new[b * HIDN + j] = (1.f - z) * n + z * ho;
  if (b == 0 && j < BN) slots[j] = 0ull;
}

// ---------- logits GEMM + global argmax via u64 atomicMax ----------
// grid 250 blocks (128 v each), 256 threads: tn = tid&15 (16 x 8 v), tb = tid>>4 (16 x 4 b)
__global__ __launch_bounds__(256) void k_logits(
    const float* __restrict__ Wout, const float* __restrict__ bout,
    const float* __restrict__ h, float* __restrict__ out_logits,
    unsigned long long* __restrict__ slots, int t, int T) {
  __shared__ float Hs[64][68];
  __shared__ float Ws[128][68];
  int v0 = blockIdx.x * 128;
  int tid = threadIdx.x;
  int tn = tid & 15, tb = tid >> 4;

  float acc[8][4];
  #pragma unroll
  for (int i = 0; i < 8; ++i) {
    float bv = bout[v0 + i * 16 + tn];
    #pragma unroll
    for (int j = 0; j < 4; ++j) acc[i][j] = bv;
  }

  for (int k0 = 0; k0 < HIDN; k0 += 64) {
    #pragma unroll
    for (int p = 0; p < 4; ++p) {
      int idx = tid + p * 256;       // 0..1023
      int r = idx >> 4, c4 = idx & 15;
      *(float4*)&Hs[r][c4 * 4] =
          *(const float4*)(h + (size_t)r * HIDN + k0 + c4 * 4);
    }
    #pragma unroll
    for (int p = 0; p < 8; ++p) {
      int idx = tid + p * 256;       // 0..2047
      int r = idx >> 4, c4 = idx & 15;
      *(float4*)&Ws[r][c4 * 4] =
          *(const float4*)(Wout + (size_t)(v0 + r) * HIDN + k0 + c4 * 4);
    }
    __syncthreads();
    #pragma unroll
    for (int k4 = 0; k4 < 16; ++k4) {
      float4 hv[4];
      #pragma unroll
      for (int j = 0; j < 4; ++j) hv[j] = *(float4*)&Hs[tb * 4 + j][k4 * 4];
      #pragma unroll
      for (int i = 0; i < 8; ++i) {
        float4 w = *(float4*)&Ws[i * 16 + tn][k4 * 4];
        #pragma unroll
        for (int j = 0; j < 4; ++j)
          acc[i][j] += w.x * hv[j].x + w.y * hv[j].y + w.z * hv[j].z + w.w * hv[j].w;
      }
    }
    __syncthreads();
  }

  #pragma unroll
  for (int j = 0; j < 4; ++j) {
    int b = tb * 4 + j;
    float* dst = out_logits + ((size_t)b * T + t) * VOCABN + v0;
    unsigned long long bk = 0ull;
    #pragma unroll
    for (int i = 0; i < 8; ++i) {
      int v = i * 16 + tn;
      float val = acc[i][j];
      dst[v] = val;
      unsigned long long pk = ((unsigned long long)ordf(val) << 32) |
                              (unsigned long long)(0xFFFFFFFFu - (unsigned)(v0 + v));
      bk = (pk > bk) ? pk : bk;
    }
    #pragma unroll
    for (int m = 1; m < 16; m <<= 1) {
      unsigned long long o = __shfl_xor(bk, m, 64);
      bk = (o > bk) ? o : bk;
    }
    if (tn == 0) atomicMax(slots + b, bk);
  }
}

// ---------- final token (t = T-1) ----------
__global__ void k_final(const unsigned long long* __restrict__ slots,
                        const int* __restrict__ done_rd,
                        float* __restrict__ out_toks, int T) {
  int b = threadIdx.x;
  if (b < BN) {
    int pred = decode_pred(slots[b]);
    int iseos = (pred == EOSID) ? 1 : 0;
    int tok = (done_rd[b] || iseos) ? 0 : pred;
    out_toks[(size_t)b * T + (T - 1)] = (float)tok;
  }
}

// ---------- launch ----------
extern "C" void kernel_launch(void* const* d_in, const int* in_sizes, int n_in,
                              void* d_out, int out_size, void* d_ws, size_t ws_size,
                              hipStream_t stream) {
  const float* feat = (const float*)d_in[0];
  const float* emb  = (const float*)d_in[1];
  const float* W_ih = (const float*)d_in[2];
  const float* W_hh = (const float*)d_in[3];
  const float* b_ih = (const float*)d_in[4];
  const float* b_hh = (const float*)d_in[5];
  const float* Wout = (const float*)d_in[6];
  const float* bout = (const float*)d_in[7];

  int L = in_sizes[0] / (BN * HIDN);
  int T = out_size / (BN * (VOCABN + 1));
  if (T <= 0) T = 20;

  float* out_toks   = (float*)d_out;
  float* out_logits = (float*)d_out + (size_t)BN * T;

  char* w = (char*)d_ws;
  float* hbuf = (float*)w;  w += (size_t)2 * BN * HIDN * sizeof(float);
  float* gi   = (float*)w;  w += (size_t)BN * 1536 * sizeof(float);
  float* gh   = (float*)w;  w += (size_t)BN * 1536 * sizeof(float);
  int*   done = (int*)w;    w += (size_t)2 * BN * sizeof(int);
  w = (char*)(((uintptr_t)w + 15) & ~(uintptr_t)15);
  unsigned long long* slots = (unsigned long long*)w;

  k_init<<<BN, 256, 0, stream>>>(feat, hbuf, L, done, slots);

  for (int t = 0; t < T; ++t) {
    const float* h_rd = hbuf + (size_t)(t & 1) * BN * HIDN;
    float* h_wr       = hbuf + (size_t)((t + 1) & 1) * BN * HIDN;
    const int* drd = done + (size_t)(t & 1) * BN;
    int* dwr       = done + (size_t)((t + 1) & 1) * BN;

    k_gates<<<192, 256, 0, stream>>>(emb, W_ih, W_hh, b_ih, b_hh, h_rd,
                                     gi, gh, slots, drd, dwr, out_toks, t, T);
    k_hup<<<BN, 512, 0, stream>>>(gi, gh, h_rd, h_wr, slots);
    k_logits<<<VOCABN / 128, 256, 0, stream>>>(Wout, bout, h_wr, out_logits,
                                               slots, t, T);
  }
  k_final<<<1, 64, 0, stream>>>(slots, done + (size_t)(T & 1) * BN, out_toks, T);
}

// Round 2
// 1081.399 us; speedup vs baseline: 2.2822x; 2.2822x over previous
//
#include <hip/hip_runtime.h>
#include <stdint.h>

#define VOCABN 32000
#define EMBEDN 256
#define HIDN   512
#define BN     64
#define SOSID  1
#define EOSID  2

typedef __attribute__((ext_vector_type(8))) short short8;
typedef __attribute__((ext_vector_type(4))) float f32x4;

// ---------- helpers ----------
__device__ __forceinline__ unsigned ordf(float f) {
  unsigned u = __float_as_uint(f);
  return (u & 0x80000000u) ? ~u : (u | 0x80000000u);
}
__device__ __forceinline__ int decode_pred(unsigned long long pk) {
  return (int)(0xFFFFFFFFu - (unsigned)(pk & 0xFFFFFFFFull));
}
__device__ __forceinline__ unsigned short f2bf(float x) {  // RNE f32->bf16
  unsigned u = __float_as_uint(x);
  unsigned r = (u + 0x7FFFu + ((u >> 16) & 1u)) >> 16;
  return (unsigned short)r;
}
__device__ __forceinline__ float bf2f(unsigned short h) {
  return __uint_as_float(((unsigned)h) << 16);
}

// ---------- init: h0 = mean(features, axis=1); zero done; zero argmax slots ----------
__global__ void k_init(const float* __restrict__ feat, float* __restrict__ h0,
                       int L, int* __restrict__ done,
                       unsigned long long* __restrict__ slots) {
  int b = blockIdx.x, tid = threadIdx.x;
  float inv = 1.0f / (float)L;
  for (int j = tid; j < HIDN; j += 256) {
    const float* p = feat + (size_t)b * L * HIDN + j;
    float s = 0.f;
    for (int l = 0; l < L; ++l) s += p[(size_t)l * HIDN];
    h0[b * HIDN + j] = s * inv;
  }
  if (b == 0 && tid < 2 * BN) done[tid] = 0;
  if (b == 1 && tid < BN) slots[tid] = 0ull;
}

// ---------- split W_out into MFMA-fragment-ordered bf16 hi/lo tiles ----------
// Tile (vt,kt): 64 lanes x 8 elems; elem j of lane l = W[vt*16+(l&15)][kt*32+(l>>4)*8+j]
// Tile id = vt*16+kt, byte base = id*2048 (hi at +0, lo at +1024, lane*16 each).
__global__ __launch_bounds__(256) void k_splitW(const float* __restrict__ W,
                                                char* __restrict__ Wsp) {
  int tid = threadIdx.x, lane = tid & 63, tl = tid >> 6;
  int tile = blockIdx.x * 4 + tl;            // 0..31999
  int vt = tile >> 4, kt = tile & 15;
  int v = vt * 16 + (lane & 15);
  int k0 = kt * 32 + ((lane >> 4) << 3);
  const float* src = W + (size_t)v * HIDN + k0;
  float xv[8];
  *(float4*)&xv[0] = *(const float4*)src;
  *(float4*)&xv[4] = *(const float4*)(src + 4);
  unsigned short h[8], l[8];
  #pragma unroll
  for (int i = 0; i < 8; ++i) {
    h[i] = f2bf(xv[i]);
    l[i] = f2bf(xv[i] - bf2f(h[i]));
  }
  uint4 H, Lw;
  H.x = (unsigned)h[0] | ((unsigned)h[1] << 16);
  H.y = (unsigned)h[2] | ((unsigned)h[3] << 16);
  H.z = (unsigned)h[4] | ((unsigned)h[5] << 16);
  H.w = (unsigned)h[6] | ((unsigned)h[7] << 16);
  Lw.x = (unsigned)l[0] | ((unsigned)l[1] << 16);
  Lw.y = (unsigned)l[2] | ((unsigned)l[3] << 16);
  Lw.z = (unsigned)l[4] | ((unsigned)l[5] << 16);
  Lw.w = (unsigned)l[6] | ((unsigned)l[7] << 16);
  char* dst = Wsp + (size_t)tile * 2048 + lane * 16;
  *(uint4*)dst = H;
  *(uint4*)(dst + 1024) = Lw;
}

// ---------- gates: gi = x @ W_ih^T + b_ih ; gh = h @ W_hh^T + b_hh ----------
__global__ __launch_bounds__(256) void k_gates(
    const float* __restrict__ emb, const float* __restrict__ W_ih,
    const float* __restrict__ W_hh, const float* __restrict__ b_ih,
    const float* __restrict__ b_hh, const float* __restrict__ h_rd,
    float* __restrict__ gi, float* __restrict__ gh,
    const unsigned long long* __restrict__ slots,
    const int* __restrict__ done_rd, int* __restrict__ done_wr,
    float* __restrict__ out_toks, int t, int T) {
  __shared__ float Xs[32][68];
  __shared__ float Ws[32][68];
  __shared__ int preds[32];

  int nt = blockIdx.x >> 1;
  int bg = blockIdx.x & 1;
  int n0 = nt * 32;
  int b0 = bg * 32;
  int tid = threadIdx.x;
  bool is_gi = (n0 < 1536);

  if (tid < 32) {
    int b = b0 + tid;
    preds[tid] = (t == 0) ? SOSID : decode_pred(slots[b]);
  }
  if (blockIdx.x == 0 && t >= 1 && tid < BN) {
    int b = tid;
    int pred = decode_pred(slots[b]);
    int iseos = (pred == EOSID) ? 1 : 0;
    int dold = done_rd[b];
    int tok = (dold || iseos) ? 0 : pred;
    out_toks[(size_t)b * T + (t - 1)] = (float)tok;
    done_wr[b] = dold | iseos;
  }
  __syncthreads();

  int K = is_gi ? EMBEDN : HIDN;
  int tn = tid & 31;
  int tb = tid >> 5;
  int nrow = n0 + tn;
  float bias = is_gi ? b_ih[nrow] : b_hh[nrow - 1536];
  float acc[4] = {bias, bias, bias, bias};
  const float* Wsrc = is_gi ? (W_ih + (size_t)n0 * EMBEDN)
                            : (W_hh + (size_t)(n0 - 1536) * HIDN);

  for (int k0 = 0; k0 < K; k0 += 64) {
    #pragma unroll
    for (int p = 0; p < 2; ++p) {
      int idx = tid + p * 256;
      int r = idx >> 4, c4 = idx & 15;
      *(float4*)&Ws[r][c4 * 4] =
          *(const float4*)(Wsrc + (size_t)r * K + k0 + c4 * 4);
      const float* src = is_gi
          ? (emb + (size_t)preds[r] * EMBEDN + k0 + c4 * 4)
          : (h_rd + (size_t)(b0 + r) * HIDN + k0 + c4 * 4);
      *(float4*)&Xs[r][c4 * 4] = *(const float4*)src;
    }
    __syncthreads();
    #pragma unroll
    for (int k4 = 0; k4 < 16; ++k4) {
      float4 w = *(float4*)&Ws[tn][k4 * 4];
      #pragma unroll
      for (int j = 0; j < 4; ++j) {
        float4 x = *(float4*)&Xs[tb * 4 + j][k4 * 4];
        acc[j] += w.x * x.x + w.y * x.y + w.z * x.z + w.w * x.w;
      }
    }
    __syncthreads();
  }

  float* dst = is_gi ? gi : gh;
  int nc = is_gi ? nrow : (nrow - 1536);
  #pragma unroll
  for (int j = 0; j < 4; ++j)
    dst[(size_t)(b0 + tb * 4 + j) * 1536 + nc] = acc[j];
}

// ---------- h update + optional bf16 hi/lo fragment split + reset slots ----------
__global__ void k_hup(const float* __restrict__ gi, const float* __restrict__ gh,
                      const float* __restrict__ h_old, float* __restrict__ h_new,
                      unsigned long long* __restrict__ slots,
                      char* __restrict__ Hsp, int do_split) {
  int b = blockIdx.x, j = threadIdx.x;  // 64 blocks x 512 threads
  const float* gib = gi + (size_t)b * 1536;
  const float* ghb = gh + (size_t)b * 1536;
  float r = 1.f / (1.f + expf(-(gib[j] + ghb[j])));
  float z = 1.f / (1.f + expf(-(gib[512 + j] + ghb[512 + j])));
  float n = tanhf(gib[1024 + j] + r * ghb[1024 + j]);
  float ho = h_old[b * HIDN + j];
  float hn = (1.f - z) * n + z * ho;
  h_new[b * HIDN + j] = hn;
  if (do_split) {
    unsigned short hi = f2bf(hn);
    unsigned short lo = f2bf(hn - bf2f(hi));
    int bt = b >> 4, col = b & 15, kt = j >> 5, kr = j & 31;
    int lane = ((kr >> 3) << 4) | col, elem = kr & 7;
    size_t off = (size_t)(bt * 16 + kt) * 2048 + lane * 16 + elem * 2;
    *(unsigned short*)(Hsp + off) = hi;
    *(unsigned short*)(Hsp + off + 1024) = lo;
  }
  if (b == 0 && j < BN) slots[j] = 0ull;
}

// ---------- logits via bf16x3 MFMA + bias + global argmax ----------
// 500 blocks x 4 waves; wave covers 32v x 32b. acc fp32 exactness ~2^-18 rel.
__global__ __launch_bounds__(256) void k_logits_mfma(
    const char* __restrict__ Wsp, const char* __restrict__ Hsp,
    const float* __restrict__ bout, float* __restrict__ out_logits,
    unsigned long long* __restrict__ slots, int t, int T) {
  int tid = threadIdx.x, lane = tid & 63, wid = tid >> 6;
  int v0 = blockIdx.x * 64 + (wid >> 1) * 32;
  int vt = v0 >> 4;                    // tiles vt, vt+1
  int bt0 = (wid & 1) * 2;             // tiles bt0, bt0+1

  f32x4 acc[2][2];
  #pragma unroll
  for (int mv = 0; mv < 2; ++mv)
    #pragma unroll
    for (int nb = 0; nb < 2; ++nb)
      acc[mv][nb] = (f32x4){0.f, 0.f, 0.f, 0.f};

  #pragma unroll 2
  for (int kt = 0; kt < 16; ++kt) {
    short8 a[2][2], bf[2][2];
    #pragma unroll
    for (int mv = 0; mv < 2; ++mv) {
      const char* p = Wsp + (size_t)((vt + mv) * 16 + kt) * 2048 + lane * 16;
      a[mv][0] = *(const short8*)p;
      a[mv][1] = *(const short8*)(p + 1024);
    }
    #pragma unroll
    for (int nb = 0; nb < 2; ++nb) {
      const char* q = Hsp + (size_t)((bt0 + nb) * 16 + kt) * 2048 + lane * 16;
      bf[nb][0] = *(const short8*)q;
      bf[nb][1] = *(const short8*)(q + 1024);
    }
    #pragma unroll
    for (int mv = 0; mv < 2; ++mv)
      #pragma unroll
      for (int nb = 0; nb < 2; ++nb) {
        acc[mv][nb] = __builtin_amdgcn_mfma_f32_16x16x32_bf16(
            a[mv][0], bf[nb][0], acc[mv][nb], 0, 0, 0);
        acc[mv][nb] = __builtin_amdgcn_mfma_f32_16x16x32_bf16(
            a[mv][0], bf[nb][1], acc[mv][nb], 0, 0, 0);
        acc[mv][nb] = __builtin_amdgcn_mfma_f32_16x16x32_bf16(
            a[mv][1], bf[nb][0], acc[mv][nb], 0, 0, 0);
      }
  }

  int col = lane & 15, rg = lane >> 4;
  unsigned long long key[2] = {0ull, 0ull};
  #pragma unroll
  for (int mv = 0; mv < 2; ++mv) {
    int vb = v0 + mv * 16 + rg * 4;
    float4 bv = *(const float4*)(bout + vb);
    #pragma unroll
    for (int nb = 0; nb < 2; ++nb) {
      int b = (bt0 + nb) * 16 + col;
      float4 vals;
      vals.x = acc[mv][nb][0] + bv.x;
      vals.y = acc[mv][nb][1] + bv.y;
      vals.z = acc[mv][nb][2] + bv.z;
      vals.w = acc[mv][nb][3] + bv.w;
      *(float4*)(out_logits + ((size_t)b * T + t) * VOCABN + vb) = vals;
      float vv[4] = {vals.x, vals.y, vals.z, vals.w};
      #pragma unroll
      for (int r = 0; r < 4; ++r) {
        unsigned long long pk = ((unsigned long long)ordf(vv[r]) << 32) |
                                (unsigned long long)(0xFFFFFFFFu - (unsigned)(vb + r));
        key[nb] = (pk > key[nb]) ? pk : key[nb];
      }
    }
  }
  #pragma unroll
  for (int nb = 0; nb < 2; ++nb) {
    unsigned long long k = key[nb];
    unsigned long long o = __shfl_xor(k, 16, 64); k = (o > k) ? o : k;
    o = __shfl_xor(k, 32, 64); k = (o > k) ? o : k;
    key[nb] = k;
  }
  if (rg == 0) atomicMax(slots + (bt0 * 16 + col), key[0]);
  if (rg == 1) atomicMax(slots + ((bt0 + 1) * 16 + col), key[1]);
}

// ---------- fallback fp32 logits (used if ws too small for W split) ----------
__global__ __launch_bounds__(256) void k_logits(
    const float* __restrict__ Wout, const float* __restrict__ bout,
    const float* __restrict__ h, float* __restrict__ out_logits,
    unsigned long long* __restrict__ slots, int t, int T) {
  __shared__ float Hs[64][68];
  __shared__ float Ws[128][68];
  int v0 = blockIdx.x * 128;
  int tid = threadIdx.x;
  int tn = tid & 15, tb = tid >> 4;

  float acc[8][4];
  #pragma unroll
  for (int i = 0; i < 8; ++i) {
    float bv = bout[v0 + i * 16 + tn];
    #pragma unroll
    for (int j = 0; j < 4; ++j) acc[i][j] = bv;
  }

  for (int k0 = 0; k0 < HIDN; k0 += 64) {
    #pragma unroll
    for (int p = 0; p < 4; ++p) {
      int idx = tid + p * 256;
      int r = idx >> 4, c4 = idx & 15;
      *(float4*)&Hs[r][c4 * 4] =
          *(const float4*)(h + (size_t)r * HIDN + k0 + c4 * 4);
    }
    #pragma unroll
    for (int p = 0; p < 8; ++p) {
      int idx = tid + p * 256;
      int r = idx >> 4, c4 = idx & 15;
      *(float4*)&Ws[r][c4 * 4] =
          *(const float4*)(Wout + (size_t)(v0 + r) * HIDN + k0 + c4 * 4);
    }
    __syncthreads();
    #pragma unroll
    for (int k4 = 0; k4 < 16; ++k4) {
      float4 hv[4];
      #pragma unroll
      for (int j = 0; j < 4; ++j) hv[j] = *(float4*)&Hs[tb * 4 + j][k4 * 4];
      #pragma unroll
      for (int i = 0; i < 8; ++i) {
        float4 w = *(float4*)&Ws[i * 16 + tn][k4 * 4];
        #pragma unroll
        for (int j = 0; j < 4; ++j)
          acc[i][j] += w.x * hv[j].x + w.y * hv[j].y + w.z * hv[j].z + w.w * hv[j].w;
      }
    }
    __syncthreads();
  }

  #pragma unroll
  for (int j = 0; j < 4; ++j) {
    int b = tb * 4 + j;
    float* dst = out_logits + ((size_t)b * T + t) * VOCABN + v0;
    unsigned long long bk = 0ull;
    #pragma unroll
    for (int i = 0; i < 8; ++i) {
      int v = i * 16 + tn;
      float val = acc[i][j];
      dst[v] = val;
      unsigned long long pk = ((unsigned long long)ordf(val) << 32) |
                              (unsigned long long)(0xFFFFFFFFu - (unsigned)(v0 + v));
      bk = (pk > bk) ? pk : bk;
    }
    #pragma unroll
    for (int m = 1; m < 16; m <<= 1) {
      unsigned long long o = __shfl_xor(bk, m, 64);
      bk = (o > bk) ? o : bk;
    }
    if (tn == 0) atomicMax(slots + b, bk);
  }
}

// ---------- final token (t = T-1) ----------
__global__ void k_final(const unsigned long long* __restrict__ slots,
                        const int* __restrict__ done_rd,
                        float* __restrict__ out_toks, int T) {
  int b = threadIdx.x;
  if (b < BN) {
    int pred = decode_pred(slots[b]);
    int iseos = (pred == EOSID) ? 1 : 0;
    int tok = (done_rd[b] || iseos) ? 0 : pred;
    out_toks[(size_t)b * T + (T - 1)] = (float)tok;
  }
}

// ---------- launch ----------
extern "C" void kernel_launch(void* const* d_in, const int* in_sizes, int n_in,
                              void* d_out, int out_size, void* d_ws, size_t ws_size,
                              hipStream_t stream) {
  const float* feat = (const float*)d_in[0];
  const float* emb  = (const float*)d_in[1];
  const float* W_ih = (const float*)d_in[2];
  const float* W_hh = (const float*)d_in[3];
  const float* b_ih = (const float*)d_in[4];
  const float* b_hh = (const float*)d_in[5];
  const float* Wout = (const float*)d_in[6];
  const float* bout = (const float*)d_in[7];

  int L = in_sizes[0] / (BN * HIDN);
  int T = out_size / (BN * (VOCABN + 1));
  if (T <= 0) T = 20;

  float* out_toks   = (float*)d_out;
  float* out_logits = (float*)d_out + (size_t)BN * T;

  char* w = (char*)d_ws;
  float* hbuf = (float*)w;  w += (size_t)2 * BN * HIDN * sizeof(float);
  float* gi   = (float*)w;  w += (size_t)BN * 1536 * sizeof(float);
  float* gh   = (float*)w;  w += (size_t)BN * 1536 * sizeof(float);
  int*   done = (int*)w;    w += (size_t)2 * BN * sizeof(int);
  w = (char*)(((uintptr_t)w + 511) & ~(uintptr_t)511);
  unsigned long long* slots = (unsigned long long*)w;
  w += 512;
  char* Hsp = w;            w += (size_t)4 * 16 * 2048;        // 128 KiB
  char* Wsp = w;            w += (size_t)32000 * 2048 / 16;    // tiles: 32000*2048 B
  // NOTE: Wsp needs 32000 tiles * 2048 B = 65,536,000 B
  size_t need = (size_t)(Wsp - (char*)d_ws) + (size_t)32000 * 2048;
  int use_mfma = (ws_size >= need) ? 1 : 0;

  k_init<<<BN, 256, 0, stream>>>(feat, hbuf, L, done, slots);
  if (use_mfma)
    k_splitW<<<32000 / 4, 256, 0, stream>>>(Wout, Wsp);

  for (int t = 0; t < T; ++t) {
    const float* h_rd = hbuf + (size_t)(t & 1) * BN * HIDN;
    float* h_wr       = hbuf + (size_t)((t + 1) & 1) * BN * HIDN;
    const int* drd = done + (size_t)(t & 1) * BN;
    int* dwr       = done + (size_t)((t + 1) & 1) * BN;

    k_gates<<<192, 256, 0, stream>>>(emb, W_ih, W_hh, b_ih, b_hh, h_rd,
                                     gi, gh, slots, drd, dwr, out_toks, t, T);
    k_hup<<<BN, 512, 0, stream>>>(gi, gh, h_rd, h_wr, slots, Hsp, use_mfma);
    if (use_mfma)
      k_logits_mfma<<<VOCABN / 64, 256, 0, stream>>>(Wsp, Hsp, bout, out_logits,
                                                     slots, t, T);
    else
      k_logits<<<VOCABN / 128, 256, 0, stream>>>(Wout, bout, h_wr, out_logits,
                                                 slots, t, T);
  }
  k_final<<<1, 64, 0, stream>>>(slots, done + (size_t)(T & 1) * BN, out_toks, T);
}

// Round 3
// 917.739 us; speedup vs baseline: 2.6892x; 1.1783x over previous
//
#include <hip/hip_runtime.h>
#include <stdint.h>

#define VOCABN 32000
#define EMBEDN 256
#define HIDN   512
#define BN     64
#define SOSID  1
#define EOSID  2

typedef __attribute__((ext_vector_type(8))) short short8;
typedef __attribute__((ext_vector_type(4))) float f32x4;

// ---------- helpers ----------
__device__ __forceinline__ unsigned ordf(float f) {
  unsigned u = __float_as_uint(f);
  return (u & 0x80000000u) ? ~u : (u | 0x80000000u);
}
__device__ __forceinline__ int decode_pred(unsigned long long pk) {
  return (int)(0xFFFFFFFFu - (unsigned)(pk & 0xFFFFFFFFull));
}
__device__ __forceinline__ unsigned short f2bf(float x) {  // RNE f32->bf16
  unsigned u = __float_as_uint(x);
  unsigned r = (u + 0x7FFFu + ((u >> 16) & 1u)) >> 16;
  return (unsigned short)r;
}
__device__ __forceinline__ float bf2f(unsigned short h) {
  return __uint_as_float(((unsigned)h) << 16);
}
__device__ __forceinline__ f32x4 mfma3(short8 ah, short8 al, short8 bh, short8 bl,
                                       f32x4 acc) {
  acc = __builtin_amdgcn_mfma_f32_16x16x32_bf16(ah, bh, acc, 0, 0, 0);
  acc = __builtin_amdgcn_mfma_f32_16x16x32_bf16(ah, bl, acc, 0, 0, 0);
  acc = __builtin_amdgcn_mfma_f32_16x16x32_bf16(al, bh, acc, 0, 0, 0);
  return acc;
}

// ---------- init: h0 = mean(features), fp32 + bf16 hi/lo fragment split ----------
__global__ void k_init(const float* __restrict__ feat, float* __restrict__ h0,
                       int L, int* __restrict__ done, char* __restrict__ Hsp0) {
  int b = blockIdx.x, tid = threadIdx.x;
  float inv = 1.0f / (float)L;
  for (int j = tid; j < HIDN; j += 256) {
    const float* p = feat + (size_t)b * L * HIDN + j;
    float s = 0.f;
    for (int l = 0; l < L; ++l) s += p[(size_t)l * HIDN];
    float hv = s * inv;
    h0[b * HIDN + j] = hv;
    unsigned short hi = f2bf(hv);
    unsigned short lo = f2bf(hv - bf2f(hi));
    int bt = b >> 4, col = b & 15, kt = j >> 5, kr = j & 31;
    int ln = ((kr >> 3) << 4) | col, e = kr & 7;
    size_t off = (size_t)(bt * 16 + kt) * 2048 + ln * 16 + e * 2;
    *(unsigned short*)(Hsp0 + off) = hi;
    *(unsigned short*)(Hsp0 + off + 1024) = lo;
  }
  if (b == 0 && tid < 2 * BN) done[tid] = 0;
}

// ---------- generic W split into MFMA-fragment-ordered bf16 hi/lo tiles ----------
// tile id = vt*(K/32)+kt; elem j of lane l = W[vt*16+(l&15)][kt*32+(l>>4)*8+j]
__global__ __launch_bounds__(256) void k_splitW(const float* __restrict__ W,
                                                char* __restrict__ Wsp,
                                                int ktshift, int K) {
  int tid = threadIdx.x, lane = tid & 63, tl = tid >> 6;
  int tile = blockIdx.x * 4 + tl;
  int vt = tile >> ktshift, kt = tile & ((1 << ktshift) - 1);
  int v = vt * 16 + (lane & 15);
  int k0 = kt * 32 + ((lane >> 4) << 3);
  const float* src = W + (size_t)v * K + k0;
  float xv[8];
  *(float4*)&xv[0] = *(const float4*)src;
  *(float4*)&xv[4] = *(const float4*)(src + 4);
  unsigned short h[8], l[8];
  #pragma unroll
  for (int i = 0; i < 8; ++i) {
    h[i] = f2bf(xv[i]);
    l[i] = f2bf(xv[i] - bf2f(h[i]));
  }
  uint4 H, Lw;
  H.x = (unsigned)h[0] | ((unsigned)h[1] << 16);
  H.y = (unsigned)h[2] | ((unsigned)h[3] << 16);
  H.z = (unsigned)h[4] | ((unsigned)h[5] << 16);
  H.w = (unsigned)h[6] | ((unsigned)h[7] << 16);
  Lw.x = (unsigned)l[0] | ((unsigned)l[1] << 16);
  Lw.y = (unsigned)l[2] | ((unsigned)l[3] << 16);
  Lw.z = (unsigned)l[4] | ((unsigned)l[5] << 16);
  Lw.w = (unsigned)l[6] | ((unsigned)l[7] << 16);
  char* dst = Wsp + (size_t)tile * 2048 + lane * 16;
  *(uint4*)dst = H;
  *(uint4*)(dst + 1024) = Lw;
}

// ---------- fused gates + GRU combine (all-MFMA, bf16x3) ----------
// 32 blocks x 256 threads. Block = hidden rows [bid*16, bid*16+16) x all 64 b.
// Wave wid = b-tile. acc_r = gi_r+gh_r (+biases), acc_z likewise, gi_n / gh_n
// kept separate (n = tanh(gi_n + r*gh_n)). Epilogue is register-local.
__global__ __launch_bounds__(256) void k_gh(
    const float* __restrict__ emb, const char* __restrict__ Wihsp,
    const char* __restrict__ Whhsp, const float* __restrict__ b_ih,
    const float* __restrict__ b_hh, const float* __restrict__ h_rd,
    float* __restrict__ h_wr, const char* __restrict__ Hsp_rd,
    char* __restrict__ Hsp_wr,
    const unsigned long long* __restrict__ slots_rd,
    unsigned long long* __restrict__ slots_wr,
    const int* __restrict__ done_rd, int* __restrict__ done_wr,
    float* __restrict__ out_toks, int t, int T) {
  __shared__ char Xlds[4 * 8 * 2048];  // 64 KiB: x split tiles [bt][kt]
  __shared__ int preds[64];
  int tid = threadIdx.x, lane = tid & 63, wid = tid >> 6;

  if (tid < 64) {
    int pr = SOSID;
    if (t) pr = decode_pred(slots_rd[tid]);
    preds[tid] = pr;
  }
  if (blockIdx.x == 0 && tid < 64) {
    slots_wr[tid] = 0ull;  // zero the buffer this step's logits will max into
    if (t >= 1) {
      int pred = decode_pred(slots_rd[tid]);
      int iseos = (pred == EOSID) ? 1 : 0;
      int dold = done_rd[tid];
      out_toks[(size_t)tid * T + (t - 1)] = (float)((dold | iseos) ? 0 : pred);
      done_wr[tid] = dold | iseos;
    }
  }
  __syncthreads();

  // stage x = emb[pred] -> bf16 hi/lo fragment tiles in LDS
  #pragma unroll 4
  for (int i = 0; i < 16; ++i) {
    int idx = i * 256 + tid;          // wave w, iter i -> row i*4+w, coalesced
    int b = idx >> 6, c4 = idx & 63;
    float4 x4 = *(const float4*)(emb + (size_t)preds[b] * EMBEDN + c4 * 4);
    int k = c4 * 4, bt = b >> 4, col = b & 15, kt = k >> 5, kr = k & 31;
    int ln = ((kr >> 3) << 4) | col, e = kr & 7;
    char* base = Xlds + ((bt * 8 + kt) * 2048 + ln * 16 + e * 2);
    float xv[4] = {x4.x, x4.y, x4.z, x4.w};
    unsigned short hi[4], lo[4];
    #pragma unroll
    for (int r = 0; r < 4; ++r) {
      hi[r] = f2bf(xv[r]);
      lo[r] = f2bf(xv[r] - bf2f(hi[r]));
    }
    uint2 Hp, Lp;
    Hp.x = (unsigned)hi[0] | ((unsigned)hi[1] << 16);
    Hp.y = (unsigned)hi[2] | ((unsigned)hi[3] << 16);
    Lp.x = (unsigned)lo[0] | ((unsigned)lo[1] << 16);
    Lp.y = (unsigned)lo[2] | ((unsigned)lo[3] << 16);
    *(uint2*)base = Hp;
    *(uint2*)(base + 1024) = Lp;
  }
  __syncthreads();

  int jt = blockIdx.x;               // r-gate vt; z: 32+jt; n: 64+jt
  int bt = wid;
  int j0 = jt * 16, rg = lane >> 4;

  float4 bir = *(const float4*)(b_ih + j0 + rg * 4);
  float4 bhr = *(const float4*)(b_hh + j0 + rg * 4);
  float4 biz = *(const float4*)(b_ih + 512 + j0 + rg * 4);
  float4 bhz = *(const float4*)(b_hh + 512 + j0 + rg * 4);
  float4 bin = *(const float4*)(b_ih + 1024 + j0 + rg * 4);
  float4 bhn = *(const float4*)(b_hh + 1024 + j0 + rg * 4);
  f32x4 acc_r = {bir.x + bhr.x, bir.y + bhr.y, bir.z + bhr.z, bir.w + bhr.w};
  f32x4 acc_z = {biz.x + bhz.x, biz.y + bhz.y, biz.z + bhz.z, biz.w + bhz.w};
  f32x4 acc_gin = {bin.x, bin.y, bin.z, bin.w};
  f32x4 acc_ghn = {bhn.x, bhn.y, bhn.z, bhn.w};

  // gi: x @ W_ih^T   (K=256 -> 8 kt tiles)
  #pragma unroll 2
  for (int kt = 0; kt < 8; ++kt) {
    const char* bq = Xlds + ((bt * 8 + kt) * 2048 + lane * 16);
    short8 xh = *(const short8*)bq;
    short8 xl = *(const short8*)(bq + 1024);
    const char* pr = Wihsp + (size_t)((jt) * 8 + kt) * 2048 + lane * 16;
    const char* pz = Wihsp + (size_t)((32 + jt) * 8 + kt) * 2048 + lane * 16;
    const char* pn = Wihsp + (size_t)((64 + jt) * 8 + kt) * 2048 + lane * 16;
    acc_r = mfma3(*(const short8*)pr, *(const short8*)(pr + 1024), xh, xl, acc_r);
    acc_z = mfma3(*(const short8*)pz, *(const short8*)(pz + 1024), xh, xl, acc_z);
    acc_gin = mfma3(*(const short8*)pn, *(const short8*)(pn + 1024), xh, xl, acc_gin);
  }
  // gh: h @ W_hh^T   (K=512 -> 16 kt tiles)
  #pragma unroll 2
  for (int kt = 0; kt < 16; ++kt) {
    const char* bq = Hsp_rd + (size_t)(bt * 16 + kt) * 2048 + lane * 16;
    short8 hh = *(const short8*)bq;
    short8 hl = *(const short8*)(bq + 1024);
    const char* pr = Whhsp + (size_t)((jt) * 16 + kt) * 2048 + lane * 16;
    const char* pz = Whhsp + (size_t)((32 + jt) * 16 + kt) * 2048 + lane * 16;
    const char* pn = Whhsp + (size_t)((64 + jt) * 16 + kt) * 2048 + lane * 16;
    acc_r = mfma3(*(const short8*)pr, *(const short8*)(pr + 1024), hh, hl, acc_r);
    acc_z = mfma3(*(const short8*)pz, *(const short8*)(pz + 1024), hh, hl, acc_z);
    acc_ghn = mfma3(*(const short8*)pn, *(const short8*)(pn + 1024), hh, hl, acc_ghn);
  }

  // epilogue: GRU combine, write h fp32 + next split tiles
  int b = bt * 16 + (lane & 15);
  int j = j0 + rg * 4;
  float4 hold = *(const float4*)(h_rd + (size_t)b * HIDN + j);
  float ho[4] = {hold.x, hold.y, hold.z, hold.w};
  float hn[4];
  unsigned short hi[4], lo[4];
  #pragma unroll
  for (int reg = 0; reg < 4; ++reg) {
    float r = 1.f / (1.f + expf(-acc_r[reg]));
    float z = 1.f / (1.f + expf(-acc_z[reg]));
    float n = tanhf(acc_gin[reg] + r * acc_ghn[reg]);
    hn[reg] = (1.f - z) * n + z * ho[reg];
    hi[reg] = f2bf(hn[reg]);
    lo[reg] = f2bf(hn[reg] - bf2f(hi[reg]));
  }
  float4 hout = {hn[0], hn[1], hn[2], hn[3]};
  *(float4*)(h_wr + (size_t)b * HIDN + j) = hout;
  int kt2 = j >> 5, kr2 = j & 31;
  int ln2 = ((kr2 >> 3) << 4) | (b & 15), e2 = kr2 & 7;
  char* dst = Hsp_wr + ((size_t)((b >> 4) * 16 + kt2) * 2048 + ln2 * 16 + e2 * 2);
  uint2 Hp, Lp;
  Hp.x = (unsigned)hi[0] | ((unsigned)hi[1] << 16);
  Hp.y = (unsigned)hi[2] | ((unsigned)hi[3] << 16);
  Lp.x = (unsigned)lo[0] | ((unsigned)lo[1] << 16);
  Lp.y = (unsigned)lo[2] | ((unsigned)lo[3] << 16);
  *(uint2*)dst = Hp;
  *(uint2*)(dst + 1024) = Lp;
}

// ---------- logits via bf16x3 MFMA, K-split for occupancy ----------
// 1000 blocks x 4 waves. Block = 32v x 64b; wave (kh=wid&1, bh=wid>>1)
// covers 32v x 32b x 8kt. kh=1 waves dump accs to LDS, kh=0 reduce + epilogue.
__global__ __launch_bounds__(256) void k_logits2(
    const char* __restrict__ Wsp, const char* __restrict__ Hsp,
    const float* __restrict__ bout, float* __restrict__ out_logits,
    unsigned long long* __restrict__ slots, int t, int T) {
  __shared__ float red[8 * 256];  // [bh][mv][nb][lane*4+r]
  int tid = threadIdx.x, lane = tid & 63, wid = tid >> 6;
  int kh = wid & 1, bh = wid >> 1;
  int v0 = blockIdx.x * 32, vt = v0 >> 4;
  int bt0 = bh * 2;

  f32x4 acc[2][2];
  #pragma unroll
  for (int mv = 0; mv < 2; ++mv)
    #pragma unroll
    for (int nb = 0; nb < 2; ++nb)
      acc[mv][nb] = (f32x4){0.f, 0.f, 0.f, 0.f};

  #pragma unroll 2
  for (int kk = 0; kk < 8; ++kk) {
    int kt = kh * 8 + kk;
    short8 a[2][2], bb[2][2];
    #pragma unroll
    for (int mv = 0; mv < 2; ++mv) {
      const char* p = Wsp + (size_t)((vt + mv) * 16 + kt) * 2048 + lane * 16;
      a[mv][0] = *(const short8*)p;
      a[mv][1] = *(const short8*)(p + 1024);
    }
    #pragma unroll
    for (int nb = 0; nb < 2; ++nb) {
      const char* q = Hsp + (size_t)((bt0 + nb) * 16 + kt) * 2048 + lane * 16;
      bb[nb][0] = *(const short8*)q;
      bb[nb][1] = *(const short8*)(q + 1024);
    }
    #pragma unroll
    for (int mv = 0; mv < 2; ++mv)
      #pragma unroll
      for (int nb = 0; nb < 2; ++nb)
        acc[mv][nb] = mfma3(a[mv][0], a[mv][1], bb[nb][0], bb[nb][1], acc[mv][nb]);
  }

  if (kh) {
    #pragma unroll
    for (int mv = 0; mv < 2; ++mv)
      #pragma unroll
      for (int nb = 0; nb < 2; ++nb)
        *(f32x4*)&red[(((bh * 2 + mv) * 2 + nb) * 256) + lane * 4] = acc[mv][nb];
  }
  __syncthreads();
  if (!kh) {
    #pragma unroll
    for (int mv = 0; mv < 2; ++mv)
      #pragma unroll
      for (int nb = 0; nb < 2; ++nb)
        acc[mv][nb] += *(f32x4*)&red[(((bh * 2 + mv) * 2 + nb) * 256) + lane * 4];

    int col = lane & 15, rg = lane >> 4;
    unsigned long long key[2] = {0ull, 0ull};
    #pragma unroll
    for (int mv = 0; mv < 2; ++mv) {
      int vb = v0 + mv * 16 + rg * 4;
      float4 bv = *(const float4*)(bout + vb);
      float bva[4] = {bv.x, bv.y, bv.z, bv.w};
      #pragma unroll
      for (int nb = 0; nb < 2; ++nb) {
        int b = (bt0 + nb) * 16 + col;
        f32x4 vals;
        #pragma unroll
        for (int r = 0; r < 4; ++r) vals[r] = acc[mv][nb][r] + bva[r];
        float* dst = out_logits + ((size_t)b * T + t) * VOCABN + vb;
        __builtin_nontemporal_store(vals, (f32x4*)dst);
        #pragma unroll
        for (int r = 0; r < 4; ++r) {
          unsigned long long pk = ((unsigned long long)ordf(vals[r]) << 32) |
                                  (unsigned long long)(0xFFFFFFFFu - (unsigned)(vb + r));
          key[nb] = (pk > key[nb]) ? pk : key[nb];
        }
      }
    }
    #pragma unroll
    for (int nb = 0; nb < 2; ++nb) {
      unsigned long long k = key[nb];
      unsigned long long o = __shfl_xor(k, 16, 64); k = (o > k) ? o : k;
      o = __shfl_xor(k, 32, 64); k = (o > k) ? o : k;
      key[nb] = k;
    }
    if (rg == 0) atomicMax(slots + (bt0 * 16 + col), key[0]);
    if (rg == 1) atomicMax(slots + ((bt0 + 1) * 16 + col), key[1]);
  }
}

// ---------- final token (t = T-1) ----------
__global__ void k_final(const unsigned long long* __restrict__ slots,
                        const int* __restrict__ done_rd,
                        float* __restrict__ out_toks, int T) {
  int b = threadIdx.x;
  if (b < BN) {
    int pred = decode_pred(slots[b]);
    int iseos = (pred == EOSID) ? 1 : 0;
    int tok = (done_rd[b] || iseos) ? 0 : pred;
    out_toks[(size_t)b * T + (T - 1)] = (float)tok;
  }
}

// ---------- launch ----------
extern "C" void kernel_launch(void* const* d_in, const int* in_sizes, int n_in,
                              void* d_out, int out_size, void* d_ws, size_t ws_size,
                              hipStream_t stream) {
  const float* feat = (const float*)d_in[0];
  const float* emb  = (const float*)d_in[1];
  const float* W_ih = (const float*)d_in[2];
  const float* W_hh = (const float*)d_in[3];
  const float* b_ih = (const float*)d_in[4];
  const float* b_hh = (const float*)d_in[5];
  const float* Wout = (const float*)d_in[6];
  const float* bout = (const float*)d_in[7];

  int L = in_sizes[0] / (BN * HIDN);
  int T = out_size / (BN * (VOCABN + 1));
  if (T <= 0) T = 20;

  float* out_toks   = (float*)d_out;
  float* out_logits = (float*)d_out + (size_t)BN * T;

  char* w = (char*)d_ws;
  float* hbuf = (float*)w;  w += (size_t)2 * BN * HIDN * sizeof(float);
  int*   done = (int*)w;    w += (size_t)2 * BN * sizeof(int);
  w = (char*)(((uintptr_t)w + 511) & ~(uintptr_t)511);
  unsigned long long* slots2 = (unsigned long long*)w;
  w += 2 * BN * sizeof(unsigned long long);
  w = (char*)(((uintptr_t)w + 511) & ~(uintptr_t)511);
  char* Hsp   = w;          w += (size_t)2 * 4 * 16 * 2048;       // 2 x 128 KiB
  char* Wihsp = w;          w += (size_t)96 * 8 * 2048;           // 1.5 MiB
  char* Whhsp = w;          w += (size_t)96 * 16 * 2048;          // 3 MiB
  char* Wsp   = w;          w += (size_t)2000 * 16 * 2048;        // 62.5 MiB

  k_init<<<BN, 256, 0, stream>>>(feat, hbuf, L, done, Hsp);
  k_splitW<<<2000 * 16 / 4, 256, 0, stream>>>(Wout, Wsp, 4, 512);
  k_splitW<<<96 * 8 / 4, 256, 0, stream>>>(W_ih, Wihsp, 3, 256);
  k_splitW<<<96 * 16 / 4, 256, 0, stream>>>(W_hh, Whhsp, 4, 512);

  for (int t = 0; t < T; ++t) {
    const float* h_rd = hbuf + (size_t)(t & 1) * BN * HIDN;
    float* h_wr       = hbuf + (size_t)((t + 1) & 1) * BN * HIDN;
    const char* Hsp_rd = Hsp + (size_t)(t & 1) * 131072;
    char* Hsp_wr       = Hsp + (size_t)((t + 1) & 1) * 131072;
    const unsigned long long* s_rd = slots2 + ((t + 1) & 1) * BN;
    unsigned long long* s_wr       = slots2 + (t & 1) * BN;
    const int* drd = done + (t & 1) * BN;
    int* dwr       = done + ((t + 1) & 1) * BN;

    k_gh<<<32, 256, 0, stream>>>(emb, Wihsp, Whhsp, b_ih, b_hh, h_rd, h_wr,
                                 Hsp_rd, Hsp_wr, s_rd, s_wr, drd, dwr,
                                 out_toks, t, T);
    k_logits2<<<VOCABN / 32, 256, 0, stream>>>(Wsp, Hsp_wr, bout, out_logits,
                                               s_wr, t, T);
  }
  k_final<<<1, 64, 0, stream>>>(slots2 + ((T - 1) & 1) * BN,
                                done + (T & 1) * BN, out_toks, T);
}

// Round 4
// 636.518 us; speedup vs baseline: 3.8773x; 1.4418x over previous
//
#include <hip/hip_runtime.h>
#include <stdint.h>

#define VOCABN 32000
#define EMBEDN 256
#define HIDN   512
#define BN     64
#define SOSID  1
#define EOSID  2
#define NSUB   8   // argmax sub-slots to spread atomic contention

typedef __attribute__((ext_vector_type(8))) short short8;
typedef __attribute__((ext_vector_type(4))) float f32x4;

// ---------- helpers ----------
__device__ __forceinline__ unsigned ordf(float f) {
  unsigned u = __float_as_uint(f);
  return (u & 0x80000000u) ? ~u : (u | 0x80000000u);
}
__device__ __forceinline__ int decode_pred(unsigned long long pk) {
  return (int)(0xFFFFFFFFu - (unsigned)(pk & 0xFFFFFFFFull));
}
__device__ __forceinline__ unsigned short f2bf(float x) {  // RNE f32->bf16
  unsigned u = __float_as_uint(x);
  unsigned r = (u + 0x7FFFu + ((u >> 16) & 1u)) >> 16;
  return (unsigned short)r;
}
__device__ __forceinline__ float bf2f(unsigned short h) {
  return __uint_as_float(((unsigned)h) << 16);
}
// acc += Ahi*Bhi + Ahi*Blo + Alo*Bhi   (bf16x3 split product)
__device__ __forceinline__ f32x4 mfma3(short8 ah, short8 al, short8 bh, short8 bl,
                                       f32x4 acc) {
  acc = __builtin_amdgcn_mfma_f32_16x16x32_bf16(ah, bh, acc, 0, 0, 0);
  acc = __builtin_amdgcn_mfma_f32_16x16x32_bf16(ah, bl, acc, 0, 0, 0);
  acc = __builtin_amdgcn_mfma_f32_16x16x32_bf16(al, bh, acc, 0, 0, 0);
  return acc;
}

// ---------- init: h0 = mean(features), fp32 + bf16 hi/lo fragment split ----------
__global__ void k_init(const float* __restrict__ feat, float* __restrict__ h0,
                       int L, int* __restrict__ done, char* __restrict__ Hsp0) {
  int b = blockIdx.x, tid = threadIdx.x;
  float inv = 1.0f / (float)L;
  for (int j = tid; j < HIDN; j += 256) {
    const float* p = feat + (size_t)b * L * HIDN + j;
    float s = 0.f;
    for (int l = 0; l < L; ++l) s += p[(size_t)l * HIDN];
    float hv = s * inv;
    h0[b * HIDN + j] = hv;
    unsigned short hi = f2bf(hv);
    unsigned short lo = f2bf(hv - bf2f(hi));
    int bt = b >> 4, col = b & 15, kt = j >> 5, kr = j & 31;
    int ln = ((kr >> 3) << 4) | col, e = kr & 7;
    size_t off = (size_t)(bt * 16 + kt) * 2048 + ln * 16 + e * 2;
    *(unsigned short*)(Hsp0 + off) = hi;
    *(unsigned short*)(Hsp0 + off + 1024) = lo;
  }
  if (b == 0 && tid < 2 * BN) done[tid] = 0;
}

// ---------- generic W split into MFMA-fragment-ordered bf16 hi/lo tiles ----------
// tile id = vt*(K/32)+kt; elem j of lane l = W[vt*16+(l&15)][kt*32+(l>>4)*8+j]
__global__ __launch_bounds__(256) void k_splitW(const float* __restrict__ W,
                                                char* __restrict__ Wsp,
                                                int ktshift, int K) {
  int tid = threadIdx.x, lane = tid & 63, tl = tid >> 6;
  int tile = blockIdx.x * 4 + tl;
  int vt = tile >> ktshift, kt = tile & ((1 << ktshift) - 1);
  int v = vt * 16 + (lane & 15);
  int k0 = kt * 32 + ((lane >> 4) << 3);
  const float* src = W + (size_t)v * K + k0;
  float xv[8];
  *(float4*)&xv[0] = *(const float4*)src;
  *(float4*)&xv[4] = *(const float4*)(src + 4);
  unsigned short h[8], l[8];
  #pragma unroll
  for (int i = 0; i < 8; ++i) {
    h[i] = f2bf(xv[i]);
    l[i] = f2bf(xv[i] - bf2f(h[i]));
  }
  uint4 H, Lw;
  H.x = (unsigned)h[0] | ((unsigned)h[1] << 16);
  H.y = (unsigned)h[2] | ((unsigned)h[3] << 16);
  H.z = (unsigned)h[4] | ((unsigned)h[5] << 16);
  H.w = (unsigned)h[6] | ((unsigned)h[7] << 16);
  Lw.x = (unsigned)l[0] | ((unsigned)l[1] << 16);
  Lw.y = (unsigned)l[2] | ((unsigned)l[3] << 16);
  Lw.z = (unsigned)l[4] | ((unsigned)l[5] << 16);
  Lw.w = (unsigned)l[6] | ((unsigned)l[7] << 16);
  char* dst = Wsp + (size_t)tile * 2048 + lane * 16;
  *(uint4*)dst = H;
  *(uint4*)(dst + 1024) = Lw;
}

// ---------- fused gates + GRU combine (all-MFMA, bf16x3) ----------
// 128 blocks (jt=bid>>2 over 32 j-tiles, bt=bid&3 over 4 b-tiles) x 4 waves.
// 24 K-units (gi: 8 of K=256, gh: 16 of K=512) split 6 per wave; LDS reduce;
// wave 0 does the register-local GRU combine + h/Hsp writes.
// x = emb[pred] loaded directly as B-fragments (no LDS staging).
__global__ __launch_bounds__(256) void k_gh(
    const float* __restrict__ emb, const char* __restrict__ Wihsp,
    const char* __restrict__ Whhsp, const float* __restrict__ b_ih,
    const float* __restrict__ b_hh, const float* __restrict__ h_rd,
    float* __restrict__ h_wr, const char* __restrict__ Hsp_rd,
    char* __restrict__ Hsp_wr,
    const unsigned long long* __restrict__ s_rd,
    unsigned long long* __restrict__ s_wr,
    const int* __restrict__ done_rd, int* __restrict__ done_wr,
    float* __restrict__ out_toks, int t, int T) {
  __shared__ int preds[16];
  __shared__ float red[3][4][256];
  int tid = threadIdx.x, lane = tid & 63, wid = tid >> 6;
  int jt = blockIdx.x >> 2, bt = blockIdx.x & 3;

  if (tid < 16) {
    int pr = SOSID;
    if (t) {
      unsigned long long mx = 0ull;
      #pragma unroll
      for (int s = 0; s < NSUB; ++s) {
        unsigned long long v = s_rd[s * BN + bt * 16 + tid];
        mx = (v > mx) ? v : mx;
      }
      pr = decode_pred(mx);
    }
    preds[tid] = pr;
  }
  if (blockIdx.x == 0) {
    s_wr[tid] = 0ull;                      // zero this step's argmax buffer
    s_wr[256 + tid] = 0ull;
    if (t >= 1 && tid < BN) {
      unsigned long long mx = 0ull;
      #pragma unroll
      for (int s = 0; s < NSUB; ++s) {
        unsigned long long v = s_rd[s * BN + tid];
        mx = (v > mx) ? v : mx;
      }
      int pred = decode_pred(mx);
      int iseos = (pred == EOSID) ? 1 : 0;
      int dold = done_rd[tid];
      out_toks[(size_t)tid * T + (t - 1)] = (float)((dold | iseos) ? 0 : pred);
      done_wr[tid] = dold | iseos;
    }
  }
  __syncthreads();

  int col = lane & 15, rg = lane >> 4;
  int xrow = preds[col];
  f32x4 acc_r = {0.f, 0.f, 0.f, 0.f}, acc_z = {0.f, 0.f, 0.f, 0.f};
  f32x4 acc_gin = {0.f, 0.f, 0.f, 0.f}, acc_ghn = {0.f, 0.f, 0.f, 0.f};

  #pragma unroll
  for (int u = 0; u < 6; ++u) {
    int g = wid * 6 + u;
    if (g < 8) {
      // gi unit: kt = g over emb row. B-frag: 8 consecutive floats of x row.
      float xv[8];
      const float* src = emb + (size_t)xrow * EMBEDN + g * 32 + rg * 8;
      *(float4*)&xv[0] = *(const float4*)src;
      *(float4*)&xv[4] = *(const float4*)(src + 4);
      unsigned short hi[8], lo[8];
      #pragma unroll
      for (int i = 0; i < 8; ++i) {
        hi[i] = f2bf(xv[i]);
        lo[i] = f2bf(xv[i] - bf2f(hi[i]));
      }
      short8 xh, xl;
      #pragma unroll
      for (int i = 0; i < 8; ++i) { xh[i] = (short)hi[i]; xl[i] = (short)lo[i]; }
      const char* pr_ = Wihsp + (size_t)((jt) * 8 + g) * 2048 + lane * 16;
      const char* pz_ = Wihsp + (size_t)((32 + jt) * 8 + g) * 2048 + lane * 16;
      const char* pn_ = Wihsp + (size_t)((64 + jt) * 8 + g) * 2048 + lane * 16;
      acc_r = mfma3(*(const short8*)pr_, *(const short8*)(pr_ + 1024), xh, xl, acc_r);
      acc_z = mfma3(*(const short8*)pz_, *(const short8*)(pz_ + 1024), xh, xl, acc_z);
      acc_gin = mfma3(*(const short8*)pn_, *(const short8*)(pn_ + 1024), xh, xl, acc_gin);
    } else {
      int kt = g - 8;
      const char* bq = Hsp_rd + (size_t)(bt * 16 + kt) * 2048 + lane * 16;
      short8 hh = *(const short8*)bq;
      short8 hl = *(const short8*)(bq + 1024);
      const char* pr_ = Whhsp + (size_t)((jt) * 16 + kt) * 2048 + lane * 16;
      const char* pz_ = Whhsp + (size_t)((32 + jt) * 16 + kt) * 2048 + lane * 16;
      const char* pn_ = Whhsp + (size_t)((64 + jt) * 16 + kt) * 2048 + lane * 16;
      acc_r = mfma3(*(const short8*)pr_, *(const short8*)(pr_ + 1024), hh, hl, acc_r);
      acc_z = mfma3(*(const short8*)pz_, *(const short8*)(pz_ + 1024), hh, hl, acc_z);
      acc_ghn = mfma3(*(const short8*)pn_, *(const short8*)(pn_ + 1024), hh, hl, acc_ghn);
    }
  }

  if (wid) {
    *(f32x4*)&red[wid - 1][0][lane * 4] = acc_r;
    *(f32x4*)&red[wid - 1][1][lane * 4] = acc_z;
    *(f32x4*)&red[wid - 1][2][lane * 4] = acc_gin;
    *(f32x4*)&red[wid - 1][3][lane * 4] = acc_ghn;
  }
  __syncthreads();
  if (wid == 0) {
    #pragma unroll
    for (int w = 0; w < 3; ++w) {
      acc_r += *(f32x4*)&red[w][0][lane * 4];
      acc_z += *(f32x4*)&red[w][1][lane * 4];
      acc_gin += *(f32x4*)&red[w][2][lane * 4];
      acc_ghn += *(f32x4*)&red[w][3][lane * 4];
    }
    int j0 = jt * 16, j = j0 + rg * 4;
    int b = bt * 16 + col;
    float4 bir = *(const float4*)(b_ih + j);
    float4 bhr = *(const float4*)(b_hh + j);
    float4 biz = *(const float4*)(b_ih + 512 + j);
    float4 bhz = *(const float4*)(b_hh + 512 + j);
    float4 bin = *(const float4*)(b_ih + 1024 + j);
    float4 bhn = *(const float4*)(b_hh + 1024 + j);
    float bra[4] = {bir.x + bhr.x, bir.y + bhr.y, bir.z + bhr.z, bir.w + bhr.w};
    float bza[4] = {biz.x + bhz.x, biz.y + bhz.y, biz.z + bhz.z, biz.w + bhz.w};
    float bia[4] = {bin.x, bin.y, bin.z, bin.w};
    float bha[4] = {bhn.x, bhn.y, bhn.z, bhn.w};
    float4 hold = *(const float4*)(h_rd + (size_t)b * HIDN + j);
    float ho[4] = {hold.x, hold.y, hold.z, hold.w};
    float hn[4];
    unsigned short hi[4], lo[4];
    #pragma unroll
    for (int reg = 0; reg < 4; ++reg) {
      float r = 1.f / (1.f + expf(-(acc_r[reg] + bra[reg])));
      float z = 1.f / (1.f + expf(-(acc_z[reg] + bza[reg])));
      float n = tanhf(acc_gin[reg] + bia[reg] + r * (acc_ghn[reg] + bha[reg]));
      hn[reg] = (1.f - z) * n + z * ho[reg];
      hi[reg] = f2bf(hn[reg]);
      lo[reg] = f2bf(hn[reg] - bf2f(hi[reg]));
    }
    float4 hout = {hn[0], hn[1], hn[2], hn[3]};
    *(float4*)(h_wr + (size_t)b * HIDN + j) = hout;
    int kt2 = j >> 5, kr2 = j & 31;
    int ln2 = ((kr2 >> 3) << 4) | col, e2 = kr2 & 7;
    char* dst = Hsp_wr + ((size_t)((b >> 4) * 16 + kt2) * 2048 + ln2 * 16 + e2 * 2);
    uint2 Hp, Lp;
    Hp.x = (unsigned)hi[0] | ((unsigned)hi[1] << 16);
    Hp.y = (unsigned)hi[2] | ((unsigned)hi[3] << 16);
    Lp.x = (unsigned)lo[0] | ((unsigned)lo[1] << 16);
    Lp.y = (unsigned)lo[2] | ((unsigned)lo[3] << 16);
    *(uint2*)dst = Hp;
    *(uint2*)(dst + 1024) = Lp;
  }
}

// ---------- logits via bf16x3 MFMA, swapped operands (A=H, B=W) ----------
// 1000 blocks x 4 waves (kh=wid&1 K-half, bh=wid>>1 b-half). Wave: 32v x 32b x 8kt.
// C layout: col(lane&15)=v within tile -> coalesced 64B stores per rg group.
__global__ __launch_bounds__(256) void k_logits3(
    const char* __restrict__ Wsp, const char* __restrict__ Hsp,
    const float* __restrict__ bout, float* __restrict__ out_logits,
    unsigned long long* __restrict__ slots, int t, int T) {
  __shared__ float red[2][2][2][256];  // [bh][nb][mv][lane*4+r]
  int tid = threadIdx.x, lane = tid & 63, wid = tid >> 6;
  int kh = wid & 1, bh = wid >> 1;
  int v0 = blockIdx.x * 32, vt = v0 >> 4;
  int bt0 = bh * 2;
  int sub = blockIdx.x & (NSUB - 1);

  f32x4 acc[2][2];  // [nb][mv]
  #pragma unroll
  for (int nb = 0; nb < 2; ++nb)
    #pragma unroll
    for (int mv = 0; mv < 2; ++mv)
      acc[nb][mv] = (f32x4){0.f, 0.f, 0.f, 0.f};

  #pragma unroll 2
  for (int kk = 0; kk < 8; ++kk) {
    int kt = kh * 8 + kk;
    short8 ah[2], al[2], wh[2], wl[2];
    #pragma unroll
    for (int nb = 0; nb < 2; ++nb) {
      const char* q = Hsp + (size_t)((bt0 + nb) * 16 + kt) * 2048 + lane * 16;
      ah[nb] = *(const short8*)q;
      al[nb] = *(const short8*)(q + 1024);
    }
    #pragma unroll
    for (int mv = 0; mv < 2; ++mv) {
      const char* p = Wsp + (size_t)((vt + mv) * 16 + kt) * 2048 + lane * 16;
      wh[mv] = *(const short8*)p;
      wl[mv] = *(const short8*)(p + 1024);
    }
    #pragma unroll
    for (int nb = 0; nb < 2; ++nb)
      #pragma unroll
      for (int mv = 0; mv < 2; ++mv)
        acc[nb][mv] = mfma3(ah[nb], al[nb], wh[mv], wl[mv], acc[nb][mv]);
  }

  if (kh) {
    #pragma unroll
    for (int nb = 0; nb < 2; ++nb)
      #pragma unroll
      for (int mv = 0; mv < 2; ++mv)
        *(f32x4*)&red[bh][nb][mv][lane * 4] = acc[nb][mv];
  }
  __syncthreads();
  if (!kh) {
    int col = lane & 15, rg = lane >> 4;
    float bvv[2];
    #pragma unroll
    for (int mv = 0; mv < 2; ++mv) bvv[mv] = bout[v0 + mv * 16 + col];
    unsigned long long key[2][4];
    #pragma unroll
    for (int nb = 0; nb < 2; ++nb)
      #pragma unroll
      for (int reg = 0; reg < 4; ++reg) key[nb][reg] = 0ull;

    #pragma unroll
    for (int nb = 0; nb < 2; ++nb) {
      #pragma unroll
      for (int mv = 0; mv < 2; ++mv) {
        f32x4 sum = acc[nb][mv] + *(f32x4*)&red[bh][nb][mv][lane * 4];
        int v = v0 + mv * 16 + col;
        #pragma unroll
        for (int reg = 0; reg < 4; ++reg) {
          float val = sum[reg] + bvv[mv];
          int b = (bt0 + nb) * 16 + rg * 4 + reg;
          __builtin_nontemporal_store(
              val, out_logits + ((size_t)b * T + t) * VOCABN + v);
          unsigned long long pk = ((unsigned long long)ordf(val) << 32) |
                                  (unsigned long long)(0xFFFFFFFFu - (unsigned)v);
          key[nb][reg] = (pk > key[nb][reg]) ? pk : key[nb][reg];
        }
      }
    }
    // reduce over the 16 lanes of each rg group (max over v)
    #pragma unroll
    for (int m = 1; m < 16; m <<= 1) {
      #pragma unroll
      for (int nb = 0; nb < 2; ++nb)
        #pragma unroll
        for (int reg = 0; reg < 4; ++reg) {
          unsigned long long o = __shfl_xor(key[nb][reg], m, 64);
          key[nb][reg] = (o > key[nb][reg]) ? o : key[nb][reg];
        }
    }
    if (col == 0) {
      #pragma unroll
      for (int nb = 0; nb < 2; ++nb)
        #pragma unroll
        for (int reg = 0; reg < 4; ++reg) {
          int b = (bt0 + nb) * 16 + rg * 4 + reg;
          atomicMax(slots + sub * BN + b, key[nb][reg]);
        }
    }
  }
}

// ---------- final token (t = T-1) ----------
__global__ void k_final(const unsigned long long* __restrict__ slots,
                        const int* __restrict__ done_rd,
                        float* __restrict__ out_toks, int T) {
  int b = threadIdx.x;
  if (b < BN) {
    unsigned long long mx = 0ull;
    #pragma unroll
    for (int s = 0; s < NSUB; ++s) {
      unsigned long long v = slots[s * BN + b];
      mx = (v > mx) ? v : mx;
    }
    int pred = decode_pred(mx);
    int iseos = (pred == EOSID) ? 1 : 0;
    int tok = (done_rd[b] || iseos) ? 0 : pred;
    out_toks[(size_t)b * T + (T - 1)] = (float)tok;
  }
}

// ---------- launch ----------
extern "C" void kernel_launch(void* const* d_in, const int* in_sizes, int n_in,
                              void* d_out, int out_size, void* d_ws, size_t ws_size,
                              hipStream_t stream) {
  const float* feat = (const float*)d_in[0];
  const float* emb  = (const float*)d_in[1];
  const float* W_ih = (const float*)d_in[2];
  const float* W_hh = (const float*)d_in[3];
  const float* b_ih = (const float*)d_in[4];
  const float* b_hh = (const float*)d_in[5];
  const float* Wout = (const float*)d_in[6];
  const float* bout = (const float*)d_in[7];

  int L = in_sizes[0] / (BN * HIDN);
  int T = out_size / (BN * (VOCABN + 1));
  if (T <= 0) T = 20;

  float* out_toks   = (float*)d_out;
  float* out_logits = (float*)d_out + (size_t)BN * T;

  char* w = (char*)d_ws;
  float* hbuf = (float*)w;  w += (size_t)2 * BN * HIDN * sizeof(float);
  int*   done = (int*)w;    w += (size_t)2 * BN * sizeof(int);
  w = (char*)(((uintptr_t)w + 511) & ~(uintptr_t)511);
  unsigned long long* slots2 = (unsigned long long*)w;   // 2 x NSUB x BN
  w += (size_t)2 * NSUB * BN * sizeof(unsigned long long);
  w = (char*)(((uintptr_t)w + 511) & ~(uintptr_t)511);
  char* Hsp   = w;          w += (size_t)2 * 4 * 16 * 2048;       // 2 x 128 KiB
  char* Wihsp = w;          w += (size_t)96 * 8 * 2048;           // 1.5 MiB
  char* Whhsp = w;          w += (size_t)96 * 16 * 2048;          // 3 MiB
  char* Wsp   = w;          w += (size_t)2000 * 16 * 2048;        // 62.5 MiB

  k_init<<<BN, 256, 0, stream>>>(feat, hbuf, L, done, Hsp);
  k_splitW<<<2000 * 16 / 4, 256, 0, stream>>>(Wout, Wsp, 4, 512);
  k_splitW<<<96 * 8 / 4, 256, 0, stream>>>(W_ih, Wihsp, 3, 256);
  k_splitW<<<96 * 16 / 4, 256, 0, stream>>>(W_hh, Whhsp, 4, 512);

  for (int t = 0; t < T; ++t) {
    const float* h_rd = hbuf + (size_t)(t & 1) * BN * HIDN;
    float* h_wr       = hbuf + (size_t)((t + 1) & 1) * BN * HIDN;
    const char* Hsp_rd = Hsp + (size_t)(t & 1) * 131072;
    char* Hsp_wr       = Hsp + (size_t)((t + 1) & 1) * 131072;
    const unsigned long long* s_rd = slots2 + ((t + 1) & 1) * NSUB * BN;
    unsigned long long* s_wr       = slots2 + (t & 1) * NSUB * BN;
    const int* drd = done + (t & 1) * BN;
    int* dwr       = done + ((t + 1) & 1) * BN;

    k_gh<<<128, 256, 0, stream>>>(emb, Wihsp, Whhsp, b_ih, b_hh, h_rd, h_wr,
                                  Hsp_rd, Hsp_wr, s_rd, s_wr, drd, dwr,
                                  out_toks, t, T);
    k_logits3<<<VOCABN / 32, 256, 0, stream>>>(Wsp, Hsp_wr, bout, out_logits,
                                               s_wr, t, T);
  }
  k_final<<<1, 64, 0, stream>>>(slots2 + ((T - 1) & 1) * NSUB * BN,
                                done + (T & 1) * BN, out_toks, T);
}